// Round 1
// baseline (697.362 us; speedup 1.0000x reference)
//
#include <hip/hip_runtime.h>
#include <math.h>

#define T_DIM 8192
#define D_DIM 7168
#define E_DIM 256
#define N_GROUPS 8
#define GROUP_SZ (E_DIM / N_GROUPS)   // 32
#define TOPK_GROUPS 4
#define TOP_K 8

#define BM 64
#define BN 64
#define BK 32

// ---------------------------------------------------------------------------
// Kernel 1: scores = sigmoid(x @ W), fp32 tiled GEMM, 64x64x32 tiles.
// A staged TRANSPOSED in LDS so inner-loop reads of both A and B are
// contiguous float4 (ds_read_b128). +4 pad keeps 16B alignment, <=2-way banks.
// ---------------------------------------------------------------------------
__global__ __launch_bounds__(256) void gemm_sigmoid_kernel(
    const float* __restrict__ x,      // [T, D] row-major
    const float* __restrict__ w,      // [D, E] row-major
    float* __restrict__ scores)       // [T, E]
{
    __shared__ float As[BK][BM + 4];  // As[k][m]  (transposed tile)
    __shared__ float Bs[BK][BN + 4];  // Bs[k][n]

    const int bn = blockIdx.x;        // 0..3   (E blocks)
    const int bm = blockIdx.y;        // 0..127 (T blocks)
    const int tid = threadIdx.x;
    const int tx = tid & 15;          // col group (4 cols each)
    const int ty = tid >> 4;          // row group (4 rows each)

    const int row0 = bm * BM;
    const int col0 = bn * BN;

    float acc[4][4];
#pragma unroll
    for (int i = 0; i < 4; i++)
#pragma unroll
        for (int j = 0; j < 4; j++) acc[i][j] = 0.0f;

    for (int k0 = 0; k0 < D_DIM; k0 += BK) {
        // ---- stage A tile (64 rows x 32 k) : 512 float4, 2 per thread ----
#pragma unroll
        for (int l = 0; l < 2; l++) {
            const int f  = tid + l * 256;
            const int r  = f >> 3;         // 0..63  (token row within tile)
            const int k4 = f & 7;          // 0..7   (float4 index along k)
            const float4 a = *(const float4*)(x + (size_t)(row0 + r) * D_DIM + k0 + k4 * 4);
            As[k4 * 4 + 0][r] = a.x;
            As[k4 * 4 + 1][r] = a.y;
            As[k4 * 4 + 2][r] = a.z;
            As[k4 * 4 + 3][r] = a.w;
        }
        // ---- stage B tile (32 k x 64 cols) : 512 float4, 2 per thread ----
#pragma unroll
        for (int l = 0; l < 2; l++) {
            const int f  = tid + l * 256;
            const int kk = f >> 4;         // 0..31
            const int n4 = f & 15;         // 0..15
            *(float4*)(&Bs[kk][n4 * 4]) =
                *(const float4*)(w + (size_t)(k0 + kk) * E_DIM + col0 + n4 * 4);
        }
        __syncthreads();

#pragma unroll
        for (int k = 0; k < BK; k++) {
            const float4 av = *(const float4*)(&As[k][ty * 4]);
            const float4 bv = *(const float4*)(&Bs[k][tx * 4]);
            const float a0 = av.x, a1 = av.y, a2 = av.z, a3 = av.w;
            const float b0 = bv.x, b1 = bv.y, b2 = bv.z, b3 = bv.w;
            acc[0][0] += a0 * b0; acc[0][1] += a0 * b1; acc[0][2] += a0 * b2; acc[0][3] += a0 * b3;
            acc[1][0] += a1 * b0; acc[1][1] += a1 * b1; acc[1][2] += a1 * b2; acc[1][3] += a1 * b3;
            acc[2][0] += a2 * b0; acc[2][1] += a2 * b1; acc[2][2] += a2 * b2; acc[2][3] += a2 * b3;
            acc[3][0] += a3 * b0; acc[3][1] += a3 * b1; acc[3][2] += a3 * b2; acc[3][3] += a3 * b3;
        }
        __syncthreads();
    }

    // ---- epilogue: sigmoid + store ----
#pragma unroll
    for (int i = 0; i < 4; i++) {
        const int r = row0 + ty * 4 + i;
        float4 o;
        o.x = 1.0f / (1.0f + expf(-acc[i][0]));
        o.y = 1.0f / (1.0f + expf(-acc[i][1]));
        o.z = 1.0f / (1.0f + expf(-acc[i][2]));
        o.w = 1.0f / (1.0f + expf(-acc[i][3]));
        *(float4*)(scores + (size_t)r * E_DIM + col0 + tx * 4) = o;
    }
}

// ---------------------------------------------------------------------------
// Kernel 2: per-token routing. ONE WAVE (64 lanes) per token, no barriers.
// Lane owns experts [4*lane, 4*lane+4). Group g = experts [32g, 32g+32)
// = lanes [8g, 8g+8) -- every lane's 4 experts lie in a single group.
// ---------------------------------------------------------------------------
__global__ __launch_bounds__(64) void router_kernel(
    const float* __restrict__ scores,   // [T, E] sigmoid scores
    const float* __restrict__ bias,     // [E]
    float* __restrict__ w_out,          // [T, TOP_K]
    float* __restrict__ i_out)          // [T, TOP_K] (indices as float)
{
    const int t = blockIdx.x;
    const int lane = threadIdx.x;

    __shared__ float sraw[E_DIM];       // unbiased sigmoid scores (for weights)

    const float* srow = scores + (size_t)t * E_DIM;
    const float4 sv = *(const float4*)(srow + lane * 4);
    const float4 bz = *(const float4*)(bias + lane * 4);

    *(float4*)(&sraw[lane * 4]) = sv;   // single-wave block: no barrier needed

    float sb[4];
    sb[0] = sv.x + bz.x; sb[1] = sv.y + bz.y; sb[2] = sv.z + bz.z; sb[3] = sv.w + bz.w;

    // ---- group top-2 sum: local top2 of 4, then 3-step xor-reduce over 8 lanes
    float m1 = -INFINITY, m2 = -INFINITY;
#pragma unroll
    for (int j = 0; j < 4; j++) {
        const float v = sb[j];
        if (v > m1) { m2 = m1; m1 = v; }
        else if (v > m2) { m2 = v; }
    }
#pragma unroll
    for (int d = 1; d < 8; d <<= 1) {
        const float o1 = __shfl_xor(m1, d);
        const float o2 = __shfl_xor(m2, d);
        const float hi = fmaxf(m1, o1);
        const float lo = fminf(m1, o1);
        m2 = fmaxf(lo, fmaxf(m2, o2));
        m1 = hi;
    }
    const float gscore = m1 + m2;       // identical across the 8 lanes of a group

    // every lane collects all 8 group scores
    float gs[N_GROUPS];
#pragma unroll
    for (int g = 0; g < N_GROUPS; g++) gs[g] = __shfl(gscore, g * 8);

    // ---- top-4 groups (tie -> lower index), replicated in every lane ----
    unsigned gmask = 0u;
#pragma unroll
    for (int r = 0; r < TOPK_GROUPS; r++) {
        int best = 0; float bv = -INFINITY;
#pragma unroll
        for (int g = 0; g < N_GROUPS; g++) {
            const bool taken = (gmask >> g) & 1u;
            if (!taken && gs[g] > bv) { bv = gs[g]; best = g; }
        }
        gmask |= (1u << best);
    }

    // ---- masked biased scores (unselected groups -> 0.0, like jnp.where) ----
    const int myg = lane >> 3;
    const float keep = ((gmask >> myg) & 1u) ? 1.0f : 0.0f;
    float v[4];
#pragma unroll
    for (int j = 0; j < 4; j++) v[j] = keep * sb[j];
    // (keep==0 -> exactly 0.0f; keep==1 -> sb)

    // ---- iterative top-8 (value desc, index asc tie-break == jax top_k) ----
    int selIdx[TOP_K];
#pragma unroll
    for (int it = 0; it < TOP_K; it++) {
        float bv = -INFINITY; int bi = E_DIM;
#pragma unroll
        for (int j = 0; j < 4; j++) {          // ascending j => ascending index
            if (v[j] > bv) { bv = v[j]; bi = 4 * lane + j; }
        }
#pragma unroll
        for (int off = 32; off > 0; off >>= 1) {
            const float ov = __shfl_down(bv, off);
            const int   oi = __shfl_down(bi, off);
            if (ov > bv || (ov == bv && oi < bi)) { bv = ov; bi = oi; }
        }
        bi = __shfl(bi, 0);                    // broadcast winner
        selIdx[it] = bi;
        if (lane == (bi >> 2)) v[bi & 3] = -INFINITY;   // remove winner
    }

    // ---- weights: gather UNBIASED scores, normalize, scale ----
    float wv[TOP_K];
    float wsum = 0.0f;
#pragma unroll
    for (int it = 0; it < TOP_K; it++) {
        wv[it] = sraw[selIdx[it]];             // broadcast LDS read
        wsum += wv[it];
    }
    const float inv = 2.5f / (wsum + 1e-20f);

#pragma unroll
    for (int it = 0; it < TOP_K; it++) {
        if (lane == it) {
            w_out[(size_t)t * TOP_K + it] = wv[it] * inv;
            i_out[(size_t)t * TOP_K + it] = (float)selIdx[it];
        }
    }
}

// ---------------------------------------------------------------------------
extern "C" void kernel_launch(void* const* d_in, const int* in_sizes, int n_in,
                              void* d_out, int out_size, void* d_ws, size_t ws_size,
                              hipStream_t stream) {
    const float* x    = (const float*)d_in[0];   // [T, D]
    const float* w    = (const float*)d_in[1];   // [D, E]
    const float* bias = (const float*)d_in[2];   // [E]

    float* scores = (float*)d_ws;                // [T, E] fp32 = 8 MB scratch
    float* w_out  = (float*)d_out;               // [T, 8] weights
    float* i_out  = w_out + (size_t)T_DIM * TOP_K; // [T, 8] indices (as float)

    dim3 ggrid(E_DIM / BN, T_DIM / BM);          // (4, 128)
    gemm_sigmoid_kernel<<<ggrid, 256, 0, stream>>>(x, w, scores);
    router_kernel<<<T_DIM, 64, 0, stream>>>(scores, bias, w_out, i_out);
}

// Round 2
// 377.193 us; speedup vs baseline: 1.8488x; 1.8488x over previous
//
#include <hip/hip_runtime.h>
#include <math.h>

#define T_DIM 8192
#define D_DIM 7168
#define E_DIM 256
#define N_GROUPS 8
#define TOPK_GROUPS 4
#define TOP_K 8

#define N_TOK 64      // tokens per GEMM block
#define BK 64         // k per staging chunk (2 MFMA k-steps)
#define WSCALE 512.0f
#define INV_WSCALE (1.0f / 512.0f)

typedef _Float16 half8 __attribute__((ext_vector_type(8)));
typedef _Float16 half4v __attribute__((ext_vector_type(4)));
typedef float floatx4 __attribute__((ext_vector_type(4)));

// ---------------------------------------------------------------------------
// Kernel 0: split W [D][E] fp32 -> wth/wtl [E][D] fp16 (transposed), x512.
// ---------------------------------------------------------------------------
__global__ __launch_bounds__(256) void wprep_kernel(
    const float* __restrict__ w, _Float16* __restrict__ wth, _Float16* __restrict__ wtl)
{
    __shared__ float tile[64][65];
    const int k0 = blockIdx.x * 64, e0 = blockIdx.y * 64;
    const int tid = threadIdx.x;
    {
        const int kk = tid >> 4, e4 = (tid & 15) * 4;
#pragma unroll
        for (int i = 0; i < 4; i++) {
            const float4 v = *(const float4*)(w + (size_t)(k0 + kk + i * 16) * E_DIM + e0 + e4);
            tile[kk + i * 16][e4 + 0] = v.x;
            tile[kk + i * 16][e4 + 1] = v.y;
            tile[kk + i * 16][e4 + 2] = v.z;
            tile[kk + i * 16][e4 + 3] = v.w;
        }
    }
    __syncthreads();
    {
        const int ee = tid >> 4, kk4 = (tid & 15) * 4;
#pragma unroll
        for (int i = 0; i < 4; i++) {
            const int e = ee + i * 16;
            half4v hh, ll;
#pragma unroll
            for (int j = 0; j < 4; j++) {
                const float v = tile[kk4 + j][e] * WSCALE;
                const _Float16 h = (_Float16)v;
                hh[j] = h;
                ll[j] = (_Float16)(v - (float)h);
            }
            *(half4v*)(wth + (size_t)(e0 + e) * D_DIM + k0 + kk4) = hh;
            *(half4v*)(wtl + (size_t)(e0 + e) * D_DIM + k0 + kk4) = ll;
        }
    }
}

// ---------------------------------------------------------------------------
// Kernel 1: split-fp16 MFMA GEMM. Block = all 256 experts x 64 tokens,
// K-split over gridDim.x. Writes raw z' = x.(512 W) partials (fp32).
// MFMA m = expert (A operand = W^T), n = token (B operand = x).
// LDS XOR-swizzle keeps reads/writes at <=2-way bank aliasing (free).
// ---------------------------------------------------------------------------
__device__ __forceinline__ void cvt_split8(const float4 v0, const float4 v1,
                                           half8& h, half8& l)
{
    float f[8] = {v0.x, v0.y, v0.z, v0.w, v1.x, v1.y, v1.z, v1.w};
#pragma unroll
    for (int j = 0; j < 8; j++) {
        const _Float16 hh = (_Float16)f[j];
        h[j] = hh;
        l[j] = (_Float16)(f[j] - (float)hh);
    }
}

template <bool CONVW>
__global__ __launch_bounds__(256, 2) void gemm_split_kernel(
    const float* __restrict__ x, const _Float16* __restrict__ wth,
    const _Float16* __restrict__ wtl, const float* __restrict__ wraw,
    float* __restrict__ partial, int kslen)
{
    __shared__ _Float16 As[2][256 * BK];   // [hi/lo][swizzled (e,k)]
    __shared__ _Float16 Bs[2][N_TOK * BK]; // [hi/lo][swizzled (t,k)]

    const int s = blockIdx.x, m = blockIdx.y;
    const int tid = threadIdx.x;
    const int k0 = s * kslen;
    const size_t t0 = (size_t)m * N_TOK;

    const int wave = tid >> 6, lane = tid & 63;
    const int lm = lane & 15, kq = lane >> 4; // fragment row / k-granule
    const int we0 = wave * 64;                // wave's expert base (4 waves x 64e)

    floatx4 acc[4][4];
#pragma unroll
    for (int mt = 0; mt < 4; mt++)
#pragma unroll
        for (int nt = 0; nt < 4; nt++) acc[mt][nt] = (floatx4)0.0f;

    for (int kc = k0; kc < k0 + kslen; kc += BK) {
        // ---- stage A (W^T tile: 256e x 64k, hi+lo) ----
        if (!CONVW) {
            const int ae = tid >> 3, akq = tid & 7;
#pragma unroll
            for (int i = 0; i < 8; i++) {
                const int e = ae + i * 32;
                const int off = e * BK + ((akq ^ (e & 7)) << 3);
                *(half8*)&As[0][off] = *(const half8*)(wth + (size_t)e * D_DIM + kc + akq * 8);
                *(half8*)&As[1][off] = *(const half8*)(wtl + (size_t)e * D_DIM + kc + akq * 8);
            }
        } else {
            // fallback: convert from raw w[k][e] (coalesced reads, scattered b16 writes)
#pragma unroll
            for (int i = 0; i < 16; i++) {
                const int f = tid + i * 256;
                const int kk = f >> 6;
                const int e4 = (f & 63) << 2;
                const float4 v = *(const float4*)(wraw + (size_t)(kc + kk) * E_DIM + e4);
                const float fv[4] = {v.x, v.y, v.z, v.w};
                const int kg = kk >> 3, ko = kk & 7;
#pragma unroll
                for (int j = 0; j < 4; j++) {
                    const int e = e4 + j;
                    const float sv = fv[j] * WSCALE;
                    const _Float16 hh = (_Float16)sv;
                    const int off = e * BK + ((kg ^ (e & 7)) << 3) + ko;
                    As[0][off] = hh;
                    As[1][off] = (_Float16)(sv - (float)hh);
                }
            }
        }
        // ---- stage B (x tile: 64t x 64k fp32 -> hi/lo fp16) ----
        {
            const int bt = tid >> 3, bkq = tid & 7;
#pragma unroll
            for (int i = 0; i < 2; i++) {
                const int t = bt + i * 32;
                const float* xp = x + (t0 + t) * (size_t)D_DIM + kc + bkq * 8;
                const float4 v0 = *(const float4*)(xp);
                const float4 v1 = *(const float4*)(xp + 4);
                half8 h, l;
                cvt_split8(v0, v1, h, l);
                const int off = t * BK + ((bkq ^ (t & 7)) << 3);
                *(half8*)&Bs[0][off] = h;
                *(half8*)&Bs[1][off] = l;
            }
        }
        __syncthreads();

        // ---- compute: 2 k-steps of 32 ----
#pragma unroll
        for (int ks = 0; ks < 2; ks++) {
            const int kqg = ks * 4 + kq; // granule 0..7
            half8 ah[4], al[4];
#pragma unroll
            for (int mt = 0; mt < 4; mt++) {
                const int e = we0 + mt * 16 + lm;
                const int off = e * BK + ((kqg ^ (e & 7)) << 3);
                ah[mt] = *(const half8*)&As[0][off];
                al[mt] = *(const half8*)&As[1][off];
            }
#pragma unroll
            for (int nt = 0; nt < 4; nt++) {
                const int t = nt * 16 + lm;
                const int off = t * BK + ((kqg ^ (t & 7)) << 3);
                const half8 bh = *(const half8*)&Bs[0][off];
                const half8 bl = *(const half8*)&Bs[1][off];
#pragma unroll
                for (int mt = 0; mt < 4; mt++) {
                    acc[mt][nt] = __builtin_amdgcn_mfma_f32_16x16x32_f16(ah[mt], bh, acc[mt][nt], 0, 0, 0);
                    acc[mt][nt] = __builtin_amdgcn_mfma_f32_16x16x32_f16(ah[mt], bl, acc[mt][nt], 0, 0, 0);
                    acc[mt][nt] = __builtin_amdgcn_mfma_f32_16x16x32_f16(al[mt], bh, acc[mt][nt], 0, 0, 0);
                }
            }
        }
        __syncthreads();
    }

    // ---- epilogue: store raw z' partials. C/D: col(token)=lane&15, row(e)=(lane>>4)*4+r
    float* pout = partial + (size_t)s * T_DIM * E_DIM;
    const int rq = lane >> 4;
#pragma unroll
    for (int nt = 0; nt < 4; nt++) {
        const size_t t = t0 + nt * 16 + lm;
#pragma unroll
        for (int mt = 0; mt < 4; mt++) {
            const int e = we0 + mt * 16 + rq * 4;
            *(floatx4*)(pout + t * E_DIM + e) = acc[mt][nt];
        }
    }
}

// ---------------------------------------------------------------------------
// Kernel 2: per-token routing. One wave per token, no barriers.
// Sums KS partials, z = sum * (1/512), score = sigmoid(z).
// ---------------------------------------------------------------------------
__global__ __launch_bounds__(64) void router_kernel(
    const float* __restrict__ partial, const float* __restrict__ bias,
    float* __restrict__ w_out, float* __restrict__ i_out, int ks)
{
    const int t = blockIdx.x;
    const int lane = threadIdx.x;

    __shared__ float sraw[E_DIM];

    float4 zv = make_float4(0.f, 0.f, 0.f, 0.f);
    for (int s = 0; s < ks; s++) {
        const float4 p = *(const float4*)(partial + (size_t)s * T_DIM * E_DIM +
                                          (size_t)t * E_DIM + lane * 4);
        zv.x += p.x; zv.y += p.y; zv.z += p.z; zv.w += p.w;
    }
    float4 sv;
    sv.x = 1.0f / (1.0f + expf(-zv.x * INV_WSCALE));
    sv.y = 1.0f / (1.0f + expf(-zv.y * INV_WSCALE));
    sv.z = 1.0f / (1.0f + expf(-zv.z * INV_WSCALE));
    sv.w = 1.0f / (1.0f + expf(-zv.w * INV_WSCALE));

    const float4 bz = *(const float4*)(bias + lane * 4);
    *(float4*)(&sraw[lane * 4]) = sv; // single wave: no barrier needed

    float sb[4];
    sb[0] = sv.x + bz.x; sb[1] = sv.y + bz.y; sb[2] = sv.z + bz.z; sb[3] = sv.w + bz.w;

    // group top-2 sum (8 lanes per group)
    float m1 = -INFINITY, m2 = -INFINITY;
#pragma unroll
    for (int j = 0; j < 4; j++) {
        const float v = sb[j];
        if (v > m1) { m2 = m1; m1 = v; }
        else if (v > m2) { m2 = v; }
    }
#pragma unroll
    for (int d = 1; d < 8; d <<= 1) {
        const float o1 = __shfl_xor(m1, d);
        const float o2 = __shfl_xor(m2, d);
        const float hi = fmaxf(m1, o1);
        const float lo = fminf(m1, o1);
        m2 = fmaxf(lo, fmaxf(m2, o2));
        m1 = hi;
    }
    const float gscore = m1 + m2;

    float gs[N_GROUPS];
#pragma unroll
    for (int g = 0; g < N_GROUPS; g++) gs[g] = __shfl(gscore, g * 8);

    unsigned gmask = 0u;
#pragma unroll
    for (int r = 0; r < TOPK_GROUPS; r++) {
        int best = 0; float bv = -INFINITY;
#pragma unroll
        for (int g = 0; g < N_GROUPS; g++) {
            const bool taken = (gmask >> g) & 1u;
            if (!taken && gs[g] > bv) { bv = gs[g]; best = g; }
        }
        gmask |= (1u << best);
    }

    const int myg = lane >> 3;
    const float keep = ((gmask >> myg) & 1u) ? 1.0f : 0.0f;
    float v[4];
#pragma unroll
    for (int j = 0; j < 4; j++) v[j] = keep * sb[j];

    int selIdx[TOP_K];
#pragma unroll
    for (int it = 0; it < TOP_K; it++) {
        float bv = -INFINITY; int bi = E_DIM;
#pragma unroll
        for (int j = 0; j < 4; j++) {
            if (v[j] > bv) { bv = v[j]; bi = 4 * lane + j; }
        }
#pragma unroll
        for (int off = 32; off > 0; off >>= 1) {
            const float ov = __shfl_down(bv, off);
            const int   oi = __shfl_down(bi, off);
            if (ov > bv || (ov == bv && oi < bi)) { bv = ov; bi = oi; }
        }
        bi = __shfl(bi, 0);
        selIdx[it] = bi;
        if (lane == (bi >> 2)) v[bi & 3] = -INFINITY;
    }

    float wv[TOP_K];
    float wsum = 0.0f;
#pragma unroll
    for (int it = 0; it < TOP_K; it++) {
        wv[it] = sraw[selIdx[it]];
        wsum += wv[it];
    }
    const float inv = 2.5f / (wsum + 1e-20f);

#pragma unroll
    for (int it = 0; it < TOP_K; it++) {
        if (lane == it) {
            w_out[(size_t)t * TOP_K + it] = wv[it] * inv;
            i_out[(size_t)t * TOP_K + it] = (float)selIdx[it];
        }
    }
}

// ---------------------------------------------------------------------------
extern "C" void kernel_launch(void* const* d_in, const int* in_sizes, int n_in,
                              void* d_out, int out_size, void* d_ws, size_t ws_size,
                              hipStream_t stream) {
    const float* x    = (const float*)d_in[0];
    const float* w    = (const float*)d_in[1];
    const float* bias = (const float*)d_in[2];

    float* w_out = (float*)d_out;
    float* i_out = w_out + (size_t)T_DIM * TOP_K;

    const size_t PART = (size_t)T_DIM * E_DIM * sizeof(float); // 8.39 MB
    const size_t WT   = (size_t)E_DIM * D_DIM * sizeof(_Float16); // 3.67 MB

    int KS; bool convw;
    if      (ws_size >= 4 * PART + 2 * WT) { KS = 4; convw = false; }
    else if (ws_size >= 2 * PART + 2 * WT) { KS = 2; convw = false; }
    else if (ws_size >= 1 * PART + 2 * WT) { KS = 1; convw = false; }
    else                                   { KS = 1; convw = true;  }

    float* partial = (float*)d_ws;
    _Float16* wth = (_Float16*)((char*)d_ws + (size_t)KS * PART);
    _Float16* wtl = wth + (size_t)E_DIM * D_DIM;

    const int kslen = D_DIM / KS;

    if (!convw) {
        wprep_kernel<<<dim3(D_DIM / 64, E_DIM / 64), 256, 0, stream>>>(w, wth, wtl);
        gemm_split_kernel<false><<<dim3(KS, T_DIM / N_TOK), 256, 0, stream>>>(
            x, wth, wtl, w, partial, kslen);
    } else {
        gemm_split_kernel<true><<<dim3(KS, T_DIM / N_TOK), 256, 0, stream>>>(
            x, wth, wtl, w, partial, kslen);
    }
    router_kernel<<<T_DIM, 64, 0, stream>>>(partial, bias, w_out, i_out, KS);
}